// Round 2
// baseline (371.767 us; speedup 1.0000x reference)
//
#include <hip/hip_runtime.h>

// Problem constants (B=16, C=64, H=W=128, num_heads=4). All tensors fp32.
#define HW    16384     // H*W
#define CPH   16        // channels per head
#define NBH   64        // B * num_heads
#define SPLITK 32       // k-split blocks per (b,h) in gram kernel
#define KPT   4         // k per thread in apply kernel (one float4)

// ws layout (floats):
//  G  : [64][16][16]   offset 0      gram, atomically accumulated
//  SX : [64][16]       offset 16384  sum x^2 per row
//  SY : [64][16]       offset 17408  sum y^2 per row
//  W  : [64][256][2]   offset 18432  {w2 = t2*M2, w1 = t1*M1} at [c*16+d]
#define WS_SX   16384
#define WS_SY   17408
#define WS_W    18432
#define WS_ZERO_BYTES (18432 * 4)

// Kernel 1: per (b,h): G[c][d] = sum_k x[c,k]*y[d,k]; SX[c]=sum x^2; SY[d]=sum y^2.
// Grid: NBH*SPLITK blocks, 256 threads. Thread t owns pair (c=t&15, d=t>>4)
// over a 512-wide k slice; float atomics reduce across the k-split.
__global__ __launch_bounds__(256) void gram_kernel(
    const float* __restrict__ x,
    const float* __restrict__ y,
    float* __restrict__ ws)
{
    const int blk = blockIdx.x;
    const int bh  = blk >> 5;              // / SPLITK
    const int ks  = (blk & (SPLITK - 1)) * (HW / SPLITK);
    const int t   = threadIdx.x;
    const int c   = t & 15;
    const int d   = t >> 4;

    const float* xrow = x + ((size_t)bh * CPH + c) * HW + ks;
    const float* yrow = y + ((size_t)bh * CPH + d) * HW + ks;

    float g = 0.f, sqx = 0.f, sqy = 0.f;
    for (int k = 0; k < HW / SPLITK; k += 4) {
        float4 xv = *reinterpret_cast<const float4*>(xrow + k);
        float4 yv = *reinterpret_cast<const float4*>(yrow + k);
        g = fmaf(xv.x, yv.x, g);
        g = fmaf(xv.y, yv.y, g);
        g = fmaf(xv.z, yv.z, g);
        g = fmaf(xv.w, yv.w, g);
        if (d == 0) {
            sqx = fmaf(xv.x, xv.x, sqx);
            sqx = fmaf(xv.y, xv.y, sqx);
            sqx = fmaf(xv.z, xv.z, sqx);
            sqx = fmaf(xv.w, xv.w, sqx);
        }
        if (c == 0) {
            sqy = fmaf(yv.x, yv.x, sqy);
            sqy = fmaf(yv.y, yv.y, sqy);
            sqy = fmaf(yv.z, yv.z, sqy);
            sqy = fmaf(yv.w, yv.w, sqy);
        }
    }
    atomicAdd(&ws[bh * 256 + c * 16 + d], g);
    if (d == 0) atomicAdd(&ws[WS_SX + bh * 16 + c], sqx);
    if (c == 0) atomicAdd(&ws[WS_SY + bh * 16 + d], sqy);
}

// Kernel 2: energy -> row softmax (attn1) + column softmax (attn2),
// temperature-scaled, stored transposed for the apply kernel.
// Grid: NBH blocks, 256 threads. Thread t holds E[i][j], i=t>>4, j=t&15.
__global__ __launch_bounds__(256) void softmax_kernel(
    float* __restrict__ ws,
    const float* __restrict__ t1p,
    const float* __restrict__ t2p)
{
    const int bh = blockIdx.x;
    const int t  = threadIdx.x;
    const int i  = t >> 4;
    const int j  = t & 15;

    __shared__ float Es[256];

    float nx = fmaxf(sqrtf(ws[WS_SX + bh * 16 + i]), 1e-12f);
    float ny = fmaxf(sqrtf(ws[WS_SY + bh * 16 + j]), 1e-12f);
    float e  = ws[bh * 256 + i * 16 + j] / (nx * ny);
    Es[t] = e;
    __syncthreads();

    // row softmax over j (fixed i): attn1[i][j]
    float rm = -1e30f;
    #pragma unroll
    for (int r = 0; r < 16; ++r) rm = fmaxf(rm, Es[i * 16 + r]);
    float rs = 0.f;
    #pragma unroll
    for (int r = 0; r < 16; ++r) rs += expf(Es[i * 16 + r] - rm);
    float a1 = expf(e - rm) / rs;

    // column softmax over rows (fixed j): exp(E[i,j]) / sum_r exp(E[r,j])
    float cm = -1e30f;
    #pragma unroll
    for (int r = 0; r < 16; ++r) cm = fmaxf(cm, Es[r * 16 + j]);
    float cs = 0.f;
    #pragma unroll
    for (int r = 0; r < 16; ++r) cs += expf(Es[r * 16 + j] - cm);
    float v2 = expf(e - cm) / cs;

    const float t1 = t1p[0];
    const float t2 = t2p[0];

    float* W = ws + WS_W + bh * 512;
    // y_att[d] = sum_c attn1[c][d]*y[c]  -> w1 stored at [c=i][d=j] comp .y
    W[(i * 16 + j) * 2 + 1] = t1 * a1;
    // x_att[d] = sum_c attn2[c][d]*x[c], attn2[c][d] = colsoftmax(E)[d][c]
    //   v2 here is colsoftmax at (row i, col j) = attn2[j][i] -> store at [c=j][d=i] comp .x
    W[(j * 16 + i) * 2 + 0] = t2 * v2;
}

// Kernel 3: out_x[d,k] = sum_c w2[c][d]*x[c,k] + y[d,k]   (channels 0..63)
//           out_y[d,k] = sum_c w1[c][d]*y[c,k] + x[d,k]   (channels 64..127)
// Grid: NBH * (HW/(256*KPT)) blocks, 256 threads, one float4 of k per thread.
__global__ __launch_bounds__(256) void apply_kernel(
    const float* __restrict__ x,
    const float* __restrict__ y,
    const float* __restrict__ ws,
    float* __restrict__ out)
{
    const int CHUNKS = HW / (256 * KPT);       // 16
    const int blk   = blockIdx.x;
    const int bh    = blk / CHUNKS;
    const int chunk = blk % CHUNKS;
    const int t     = threadIdx.x;
    const int k0    = chunk * (256 * KPT) + t * KPT;

    __shared__ float2 Ws[256];
    Ws[t] = reinterpret_cast<const float2*>(ws + WS_W)[bh * 256 + t];
    __syncthreads();

    const int b = bh >> 2;
    const int h = bh & 3;

    const float* xbase = x + ((size_t)bh * CPH) * HW + k0;
    const float* ybase = y + ((size_t)bh * CPH) * HW + k0;

    float accx[16][KPT];
    float accy[16][KPT];
    #pragma unroll
    for (int d = 0; d < 16; ++d)
        #pragma unroll
        for (int j = 0; j < KPT; ++j) { accx[d][j] = 0.f; accy[d][j] = 0.f; }

    #pragma unroll
    for (int c = 0; c < 16; ++c) {
        float4 xq = *reinterpret_cast<const float4*>(xbase + (size_t)c * HW);
        float4 yq = *reinterpret_cast<const float4*>(ybase + (size_t)c * HW);
        float xv[KPT] = {xq.x, xq.y, xq.z, xq.w};
        float yv[KPT] = {yq.x, yq.y, yq.z, yq.w};
        #pragma unroll
        for (int d = 0; d < 16; ++d) {
            float2 w = Ws[c * 16 + d];
            #pragma unroll
            for (int j = 0; j < KPT; ++j) accx[d][j] = fmaf(w.x, xv[j], accx[d][j]);
            #pragma unroll
            for (int j = 0; j < KPT; ++j) accy[d][j] = fmaf(w.y, yv[j], accy[d][j]);
        }
        // residual fold at d == c:  x_ += y[d],  y_ += x[d]
        #pragma unroll
        for (int j = 0; j < KPT; ++j) accx[c][j] += yv[j];
        #pragma unroll
        for (int j = 0; j < KPT; ++j) accy[c][j] += xv[j];
    }

    const size_t obx = ((size_t)b * 128 + h * 16) * HW + k0;   // x_ -> channels 0..63
    const size_t oby = obx + (size_t)64 * HW;                  // y_ -> channels 64..127
    #pragma unroll
    for (int d = 0; d < 16; ++d) {
        float4 px = make_float4(accx[d][0], accx[d][1], accx[d][2], accx[d][3]);
        float4 py = make_float4(accy[d][0], accy[d][1], accy[d][2], accy[d][3]);
        *reinterpret_cast<float4*>(out + obx + (size_t)d * HW) = px;
        *reinterpret_cast<float4*>(out + oby + (size_t)d * HW) = py;
    }
}

extern "C" void kernel_launch(void* const* d_in, const int* in_sizes, int n_in,
                              void* d_out, int out_size, void* d_ws, size_t ws_size,
                              hipStream_t stream) {
    const float* x  = (const float*)d_in[0];
    const float* y  = (const float*)d_in[1];
    const float* t1 = (const float*)d_in[2];
    const float* t2 = (const float*)d_in[3];
    float* ws  = (float*)d_ws;
    float* out = (float*)d_out;

    hipMemsetAsync(d_ws, 0, WS_ZERO_BYTES, stream);
    gram_kernel<<<NBH * SPLITK, 256, 0, stream>>>(x, y, ws);
    softmax_kernel<<<NBH, 256, 0, stream>>>(ws, t1, t2);
    apply_kernel<<<NBH * (HW / (256 * KPT)), 256, 0, stream>>>(x, y, ws, out);
}

// Round 3
// 278.610 us; speedup vs baseline: 1.3344x; 1.3344x over previous
//
#include <hip/hip_runtime.h>

// Problem constants (B=16, C=64, H=W=128, num_heads=4). All tensors fp32.
#define HW    16384     // H*W
#define CPH   16        // channels per head
#define NBH   64        // B * num_heads
#define KSLICE 2048     // k columns per gram block (8 blocks per bh)
#define TKT   256       // k columns per LDS tile
#define LS    260       // LDS row stride in floats (16B-aligned, bank-spread w/ strided c)
#define KPT   4         // k per thread in apply kernel (one float4)

// ws layout (floats):
//  G  : [64][16][16]   offset 0      gram, atomically accumulated
//  SX : [64][16]       offset 16384  sum x^2 per row
//  SY : [64][16]       offset 17408  sum y^2 per row
//  W  : [64][256][2]   offset 18432  {w2 = t2*M2, w1 = t1*M1} at [c*16+d]
#define WS_SX   16384
#define WS_SY   17408
#define WS_W    18432
#define WS_ZERO_BYTES (18432 * 4)

// Kernel 1: per (b,h): G[c][d] = sum_k x[c,k]*y[d,k]; SX[c]; SY[d].
// Grid: NBH*8 blocks, 256 threads. LDS-tiled: stage 16x256 of x,y coalesced
// (each element fetched once), then 16 k-groups x 16 threads compute 4x4
// register tiles with strided c/d (c = c0+4i) for bank-conflict-free reads.
__global__ __launch_bounds__(256) void gram_kernel(
    const float* __restrict__ x,
    const float* __restrict__ y,
    float* __restrict__ ws)
{
    __shared__ float xs[16 * LS];
    __shared__ float ys[16 * LS];
    __shared__ float Gs[256];
    __shared__ float sxs[16], sys[16];

    const int blk = blockIdx.x;
    const int bh  = blk >> 3;
    const int ks  = (blk & 7) * KSLICE;
    const int t   = threadIdx.x;

    Gs[t] = 0.f;
    if (t < 16) { sxs[t] = 0.f; sys[t] = 0.f; }

    const int c0 = t & 3;          // strided c base
    const int d0 = (t >> 2) & 3;   // strided d base
    const int g  = t >> 4;         // k-group (16 cols per tile)

    float acc[4][4];
    #pragma unroll
    for (int i = 0; i < 4; ++i)
        #pragma unroll
        for (int j = 0; j < 4; ++j) acc[i][j] = 0.f;
    float sqx[4] = {0.f, 0.f, 0.f, 0.f};
    float sqy[4] = {0.f, 0.f, 0.f, 0.f};

    const float* xb = x + (size_t)bh * CPH * HW + ks;
    const float* yb = y + (size_t)bh * CPH * HW + ks;

    for (int kt = 0; kt < KSLICE; kt += TKT) {
        __syncthreads();   // previous tile fully consumed (also covers Gs init)
        #pragma unroll
        for (int i = 0; i < 4; ++i) {
            int idx = i * 256 + t;
            int row = idx >> 6;
            int col = (idx & 63) * 4;
            float4 xv = *reinterpret_cast<const float4*>(xb + (size_t)row * HW + kt + col);
            float4 yv = *reinterpret_cast<const float4*>(yb + (size_t)row * HW + kt + col);
            *reinterpret_cast<float4*>(&xs[row * LS + col]) = xv;
            *reinterpret_cast<float4*>(&ys[row * LS + col]) = yv;
        }
        __syncthreads();

        // group g owns columns [g*16, g*16+16) of this tile
        #pragma unroll
        for (int kq = 0; kq < 16; kq += 4) {
            float4 xr[4], yr[4];
            #pragma unroll
            for (int i = 0; i < 4; ++i)
                xr[i] = *reinterpret_cast<const float4*>(&xs[(c0 + 4 * i) * LS + g * 16 + kq]);
            #pragma unroll
            for (int j = 0; j < 4; ++j)
                yr[j] = *reinterpret_cast<const float4*>(&ys[(d0 + 4 * j) * LS + g * 16 + kq]);
            #pragma unroll
            for (int i = 0; i < 4; ++i)
                #pragma unroll
                for (int j = 0; j < 4; ++j) {
                    acc[i][j] = fmaf(xr[i].x, yr[j].x, acc[i][j]);
                    acc[i][j] = fmaf(xr[i].y, yr[j].y, acc[i][j]);
                    acc[i][j] = fmaf(xr[i].z, yr[j].z, acc[i][j]);
                    acc[i][j] = fmaf(xr[i].w, yr[j].w, acc[i][j]);
                }
            if (d0 == 0) {
                #pragma unroll
                for (int i = 0; i < 4; ++i) {
                    sqx[i] = fmaf(xr[i].x, xr[i].x, sqx[i]);
                    sqx[i] = fmaf(xr[i].y, xr[i].y, sqx[i]);
                    sqx[i] = fmaf(xr[i].z, xr[i].z, sqx[i]);
                    sqx[i] = fmaf(xr[i].w, xr[i].w, sqx[i]);
                }
            }
            if (c0 == 0) {
                #pragma unroll
                for (int j = 0; j < 4; ++j) {
                    sqy[j] = fmaf(yr[j].x, yr[j].x, sqy[j]);
                    sqy[j] = fmaf(yr[j].y, yr[j].y, sqy[j]);
                    sqy[j] = fmaf(yr[j].z, yr[j].z, sqy[j]);
                    sqy[j] = fmaf(yr[j].w, yr[j].w, sqy[j]);
                }
            }
        }
    }

    // block-level reduction in LDS, then one global atomic per entry
    #pragma unroll
    for (int i = 0; i < 4; ++i)
        #pragma unroll
        for (int j = 0; j < 4; ++j)
            atomicAdd(&Gs[(c0 + 4 * i) * 16 + (d0 + 4 * j)], acc[i][j]);
    if (d0 == 0) {
        #pragma unroll
        for (int i = 0; i < 4; ++i) atomicAdd(&sxs[c0 + 4 * i], sqx[i]);
    }
    if (c0 == 0) {
        #pragma unroll
        for (int j = 0; j < 4; ++j) atomicAdd(&sys[d0 + 4 * j], sqy[j]);
    }
    __syncthreads();
    atomicAdd(&ws[bh * 256 + t], Gs[t]);
    if (t < 16)       atomicAdd(&ws[WS_SX + bh * 16 + t], sxs[t]);
    else if (t < 32)  atomicAdd(&ws[WS_SY + bh * 16 + (t - 16)], sys[t - 16]);
}

// Kernel 2: energy -> row softmax (attn1) + column softmax (attn2),
// temperature-scaled, stored transposed for the apply kernel.
__global__ __launch_bounds__(256) void softmax_kernel(
    float* __restrict__ ws,
    const float* __restrict__ t1p,
    const float* __restrict__ t2p)
{
    const int bh = blockIdx.x;
    const int t  = threadIdx.x;
    const int i  = t >> 4;
    const int j  = t & 15;

    __shared__ float Es[256];

    float nx = fmaxf(sqrtf(ws[WS_SX + bh * 16 + i]), 1e-12f);
    float ny = fmaxf(sqrtf(ws[WS_SY + bh * 16 + j]), 1e-12f);
    float e  = ws[bh * 256 + i * 16 + j] / (nx * ny);
    Es[t] = e;
    __syncthreads();

    float rm = -1e30f;
    #pragma unroll
    for (int r = 0; r < 16; ++r) rm = fmaxf(rm, Es[i * 16 + r]);
    float rs = 0.f;
    #pragma unroll
    for (int r = 0; r < 16; ++r) rs += expf(Es[i * 16 + r] - rm);
    float a1 = expf(e - rm) / rs;

    float cm = -1e30f;
    #pragma unroll
    for (int r = 0; r < 16; ++r) cm = fmaxf(cm, Es[r * 16 + j]);
    float cs = 0.f;
    #pragma unroll
    for (int r = 0; r < 16; ++r) cs += expf(Es[r * 16 + j] - cm);
    float v2 = expf(e - cm) / cs;

    const float t1 = t1p[0];
    const float t2 = t2p[0];

    float* W = ws + WS_W + bh * 512;
    W[(i * 16 + j) * 2 + 1] = t1 * a1;   // w1[c=i][d=j]
    W[(j * 16 + i) * 2 + 0] = t2 * v2;   // w2[c=j][d=i]
}

// Kernel 3: out_x[d,k] = sum_c w2[c][d]*x[c,k] + y[d,k]   (channels 0..63)
//           out_y[d,k] = sum_c w1[c][d]*y[c,k] + x[d,k]   (channels 64..127)
__global__ __launch_bounds__(256) void apply_kernel(
    const float* __restrict__ x,
    const float* __restrict__ y,
    const float* __restrict__ ws,
    float* __restrict__ out)
{
    const int CHUNKS = HW / (256 * KPT);       // 16
    const int blk   = blockIdx.x;
    const int bh    = blk / CHUNKS;
    const int chunk = blk % CHUNKS;
    const int t     = threadIdx.x;
    const int k0    = chunk * (256 * KPT) + t * KPT;

    __shared__ float2 Ws[256];
    Ws[t] = reinterpret_cast<const float2*>(ws + WS_W)[bh * 256 + t];
    __syncthreads();

    const int b = bh >> 2;
    const int h = bh & 3;

    const float* xbase = x + ((size_t)bh * CPH) * HW + k0;
    const float* ybase = y + ((size_t)bh * CPH) * HW + k0;

    float accx[16][KPT];
    float accy[16][KPT];
    #pragma unroll
    for (int d = 0; d < 16; ++d)
        #pragma unroll
        for (int j = 0; j < KPT; ++j) { accx[d][j] = 0.f; accy[d][j] = 0.f; }

    float4 xq = *reinterpret_cast<const float4*>(xbase);
    float4 yq = *reinterpret_cast<const float4*>(ybase);
    #pragma unroll
    for (int c = 0; c < 16; ++c) {
        float4 xn, yn;
        if (c < 15) {   // prefetch next row while doing this row's FMAs
            xn = *reinterpret_cast<const float4*>(xbase + (size_t)(c + 1) * HW);
            yn = *reinterpret_cast<const float4*>(ybase + (size_t)(c + 1) * HW);
        }
        float xv[KPT] = {xq.x, xq.y, xq.z, xq.w};
        float yv[KPT] = {yq.x, yq.y, yq.z, yq.w};
        #pragma unroll
        for (int d = 0; d < 16; ++d) {
            float2 w = Ws[c * 16 + d];
            #pragma unroll
            for (int j = 0; j < KPT; ++j) accx[d][j] = fmaf(w.x, xv[j], accx[d][j]);
            #pragma unroll
            for (int j = 0; j < KPT; ++j) accy[d][j] = fmaf(w.y, yv[j], accy[d][j]);
        }
        // residual fold at d == c:  x_ += y[d],  y_ += x[d]
        #pragma unroll
        for (int j = 0; j < KPT; ++j) accx[c][j] += yv[j];
        #pragma unroll
        for (int j = 0; j < KPT; ++j) accy[c][j] += xv[j];
        xq = xn; yq = yn;
    }

    const size_t obx = ((size_t)b * 128 + h * 16) * HW + k0;   // x_ -> channels 0..63
    const size_t oby = obx + (size_t)64 * HW;                  // y_ -> channels 64..127
    #pragma unroll
    for (int d = 0; d < 16; ++d) {
        float4 px = make_float4(accx[d][0], accx[d][1], accx[d][2], accx[d][3]);
        float4 py = make_float4(accy[d][0], accy[d][1], accy[d][2], accy[d][3]);
        *reinterpret_cast<float4*>(out + obx + (size_t)d * HW) = px;
        *reinterpret_cast<float4*>(out + oby + (size_t)d * HW) = py;
    }
}

extern "C" void kernel_launch(void* const* d_in, const int* in_sizes, int n_in,
                              void* d_out, int out_size, void* d_ws, size_t ws_size,
                              hipStream_t stream) {
    const float* x  = (const float*)d_in[0];
    const float* y  = (const float*)d_in[1];
    const float* t1 = (const float*)d_in[2];
    const float* t2 = (const float*)d_in[3];
    float* ws  = (float*)d_ws;
    float* out = (float*)d_out;

    hipMemsetAsync(d_ws, 0, WS_ZERO_BYTES, stream);
    gram_kernel<<<NBH * 8, 256, 0, stream>>>(x, y, ws);
    softmax_kernel<<<NBH, 256, 0, stream>>>(ws, t1, t2);
    apply_kernel<<<NBH * (HW / (256 * KPT)), 256, 0, stream>>>(x, y, ws, out);
}